// Round 7
// baseline (513.654 us; speedup 1.0000x reference)
//
#include <hip/hip_runtime.h>

#define NROW 16384
#define ROWI 10246
#define NSLICE 5                  // 0=G, 1=D, 2=A(q0), 3=A(q1), 4=A(q2)
#define POUT_F (NSLICE*33*16384)
#define NSLOT 323                 // B slots: 0..320 = tiles, 321 = D@t0, 322 = A@t69
#define BF_U16 ((size_t)NSLOT*3*64*8)
#define PTAB_ROWS 3438
#define PTAB_F (PTAB_ROWS*64)

typedef unsigned int u32;
typedef unsigned short u16;
typedef short short8 __attribute__((ext_vector_type(8)));
typedef float f32x4 __attribute__((ext_vector_type(4)));

union AFrag { u32 u[4]; short8 s; };
union BFrag { uint4 v; short8 s; };

// ---------------- prep: B fragment table (bf16, MFMA layout) ----------------
// frag id = (slot*3 + f)*64 + lane. f<2: weights, d = f*16 + (lane&15).
// f==2: count column (d==0 holds segment mask, all else 0).
// k = t*32 + (lane>>4)*8 + e. Values masked to the slot's segment.
__global__ void prep_bf(const float* __restrict__ Wg, const float* __restrict__ Wd,
                        const float* __restrict__ Wa, u16* __restrict__ Bf) {
  int id = blockIdx.x*256 + threadIdx.x;
  if (id >= NSLOT*3*64) return;
  int lane = id & 63, f = (id >> 6) % 3, slot = id / 192;
  int t   = (slot == 321) ? 0 : (slot == 322) ? 69 : slot;
  int seg = (slot == 0) ? 0 : (slot <= 69) ? 1 : (slot <= 320) ? 2
            : (slot == 321) ? 1 : 2;                  // 0=G,1=D,2=A
  int clo = (seg == 0) ? 1  : (seg == 1) ? 26   : 2212;
  int chi = (seg == 0) ? 26 : (seg == 1) ? 2212 : 10242;
  int d  = f*16 + (lane & 15);
  int kb = t*32 + (lane >> 4)*8;
  u16 o[8];
  #pragma unroll
  for (int e = 0; e < 8; ++e) {
    int c = kb + e;
    bool in = (c >= clo && c < chi);
    float v = 0.f;
    if (f == 2) {
      v = (in && (lane & 15) == 0) ? 1.f : 0.f;
    } else if (in) {
      if (seg == 0)      v = Wg[d*25   + (c-1)];
      else if (seg == 1) v = Wd[d*2186 + (c-26)];
      else               v = Wa[d*8030 + (c-2212)];
    }
    u32 bits = __float_as_uint(v);                    // RNE float->bf16
    o[e] = (u16)((bits + 0x7FFFu + ((bits >> 16) & 1u)) >> 16);
  }
  uint4 w;
  w.x = (u32)o[0] | ((u32)o[1] << 16);
  w.y = (u32)o[2] | ((u32)o[3] << 16);
  w.z = (u32)o[4] | ((u32)o[5] << 16);
  w.w = (u32)o[6] | ((u32)o[7] << 16);
  *(uint4*)&Bf[(size_t)id*8] = w;
}

// ---------------- prep: folded index-embedding table ----------------
__global__ void prep_p(const float* __restrict__ er, const float* __restrict__ eg,
                       const float* __restrict__ ea, const float* __restrict__ eo,
                       const float* __restrict__ ez, const float* __restrict__ W1,
                       float* __restrict__ P) {
  int id = blockIdx.x*256 + threadIdx.x;
  if (id >= PTAB_F) return;
  int r = id >> 6, o = id & 63;
  const float* emb; int woff;
  if (r < 6)       { emb = er + r*32;       woff = 0;   }
  else if (r < 8)  { emb = eg + (r-6)*32;   woff = 128; }
  else if (r < 15) { emb = ea + (r-8)*32;   woff = 160; }
  else if (r < 36) { emb = eo + (r-15)*32;  woff = 192; }
  else             { emb = ez + (r-36)*32;  woff = 224; }
  const float* w = W1 + o*256 + woff;
  float s = 0.f;
  #pragma unroll
  for (int c2 = 0; c2 < 32; ++c2) s += emb[c2]*w[c2];
  P[id] = s;
}

__global__ void prep_w2t(const float* __restrict__ W2, float* __restrict__ W2t) {
  int id = blockIdx.x*256 + threadIdx.x;
  if (id >= 64*64) return;
  int o = id >> 6, o2 = id & 63;
  W2t[o*64 + o2] = W2[o2*64 + o];
}

// ---------------- fused stream + MFMA bag kernel ----------------
// Wave = 16 rows; block = 4 waves = 64 rows; blockIdx.y = K-third q.
// q0: tiles [0,107) (has G@0, D [1,70), A [70,107)); q1: [107,214); q2: [214,320).
// A: row = lane&15, k = (lane>>4)*8+e.  D: col = lane&15, row = (lane>>4)*4+reg.
__global__ __launch_bounds__(256, 3) void kmain(
    const int* __restrict__ x, const u16* __restrict__ Bf, float* __restrict__ pout) {
  const int lane = threadIdx.x & 63;
  const int wv   = threadIdx.x >> 6;
  const int q    = blockIdx.y;
  const bool q0  = (q == 0);
  const int row0w = blockIdx.x*64 + wv*16;
  const int r = lane & 15, g = lane >> 4;

  const int tb   = q*107;
  const int nt   = (q == 2) ? 106 : 107;
  const int tmax = tb + nt - 1;

  const int2*  pA  = (const int2*)(x + (size_t)(row0w + r)*ROWI) + g*4;  // + t*16 + j
  const uint4* pBL = (const uint4*)Bf + lane;                            // + (t*3+f)*64

  f32x4 z = {0.f,0.f,0.f,0.f};
  f32x4 gg0=z, gg1=z, ggc=z, dd0=z, dd1=z, ddc=z, aa0=z, aa1=z, aac=z;

  int2 rA0[4], rA1[4], rA2[4], rA3[4];
  uint4 rB00, rB01, rB02, rB10, rB11, rB12;

#define LOADA(S, T) do { int _t = (T); if (_t > tmax) _t = tmax;               \
    const int2* _ap = pA + (size_t)_t*16;                                      \
    rA##S[0]=_ap[0]; rA##S[1]=_ap[1]; rA##S[2]=_ap[2]; rA##S[3]=_ap[3]; } while(0)
#define LOADB(BS, T) do { int _t = (T); if (_t > tmax) _t = tmax;              \
    const uint4* _bp = pBL + (size_t)_t*192;                                   \
    rB##BS##0=_bp[0]; rB##BS##1=_bp[64]; rB##BS##2=_bp[128]; } while(0)
#define MFMA3(P, BS) do { BFrag _b0,_b1,_b2;                                   \
    _b0.v=rB##BS##0; _b1.v=rB##BS##1; _b2.v=rB##BS##2;                         \
    P##0 = __builtin_amdgcn_mfma_f32_16x16x32_bf16(af.s, _b0.s, P##0, 0,0,0);  \
    P##1 = __builtin_amdgcn_mfma_f32_16x16x32_bf16(af.s, _b1.s, P##1, 0,0,0);  \
    P##c = __builtin_amdgcn_mfma_f32_16x16x32_bf16(af.s, _b2.s, P##c, 0,0,0); } while(0)
#define MFMA3E(P, SLOT) do { BFrag _e0,_e1,_e2;                                \
    _e0.v = pBL[(SLOT)*192]; _e1.v = pBL[(SLOT)*192+64];                       \
    _e2.v = pBL[(SLOT)*192+128];                                               \
    P##0 = __builtin_amdgcn_mfma_f32_16x16x32_bf16(af.s, _e0.s, P##0, 0,0,0);  \
    P##1 = __builtin_amdgcn_mfma_f32_16x16x32_bf16(af.s, _e1.s, P##1, 0,0,0);  \
    P##c = __builtin_amdgcn_mfma_f32_16x16x32_bf16(af.s, _e2.s, P##c, 0,0,0); } while(0)
#define PHASE(S, BS, TT) do {                                                  \
    const int tt = (TT);                                                       \
    AFrag af;                                                                  \
    af.u[0] = __umul24((u32)(rA##S[0].x + (rA##S[0].y << 16)), 0x3F80u);       \
    af.u[1] = __umul24((u32)(rA##S[1].x + (rA##S[1].y << 16)), 0x3F80u);       \
    af.u[2] = __umul24((u32)(rA##S[2].x + (rA##S[2].y << 16)), 0x3F80u);       \
    af.u[3] = __umul24((u32)(rA##S[3].x + (rA##S[3].y << 16)), 0x3F80u);       \
    if (!q0)            { MFMA3(aa, BS); }                                     \
    else if (tt == 0)   { MFMA3(gg, BS); MFMA3E(dd, 321); }                    \
    else if (tt == 69)  { MFMA3(dd, BS); MFMA3E(aa, 322); }                    \
    else if (tt < 69)   { MFMA3(dd, BS); }                                     \
    else                { MFMA3(aa, BS); }                                     \
    LOADB(BS, tt + 2);                                                         \
    LOADA(S, tt + 4);                                                          \
  } while (0)

  LOADA(0, tb); LOADA(1, tb+1); LOADA(2, tb+2); LOADA(3, tb+3);
  LOADB(0, tb); LOADB(1, tb+1);

  int t = tb;
  const int ngrp = nt >> 2;
  for (int i = 0; i < ngrp; ++i, t += 4) {
    PHASE(0, 0, t); PHASE(1, 1, t+1); PHASE(2, 0, t+2); PHASE(3, 1, t+3);
  }
  const int rem = nt & 3;
  if (rem > 0) PHASE(0, 0, t);
  if (rem > 1) PHASE(1, 1, t+1);
  if (rem > 2) PHASE(2, 0, t+2);

#define STO(P, SL) do { float* bp = pout + (size_t)(SL)*33*16384;              \
    _Pragma("unroll")                                                          \
    for (int q2 = 0; q2 < 4; ++q2) {                                           \
      bp[(size_t)r*16384      + row0w + g*4 + q2] = P##0[q2];                  \
      bp[(size_t)(16+r)*16384 + row0w + g*4 + q2] = P##1[q2];                  \
    }                                                                          \
    if (r == 0) { _Pragma("unroll")                                            \
      for (int q2 = 0; q2 < 4; ++q2)                                           \
        bp[(size_t)32*16384 + row0w + g*4 + q2] = P##c[q2]; } } while (0)

  if (q0) { STO(gg, 0); STO(dd, 1); STO(aa, 2); }
  else    { STO(aa, 2 + q); }
#undef STO
#undef PHASE
#undef MFMA3E
#undef MFMA3
#undef LOADB
#undef LOADA
}

// ---------------- reduce + tail + MLP kernel ----------------
__global__ __launch_bounds__(64, 1) void k2(
    const int* __restrict__ x, const float* __restrict__ pout,
    const float* __restrict__ Wa, const float* __restrict__ P,
    const float* __restrict__ W1, const float* __restrict__ b1,
    const float* __restrict__ W2t, const float* __restrict__ b2,
    const float* __restrict__ Wout, const float* __restrict__ bout,
    float* __restrict__ out) {
  const int row = blockIdx.x*64 + threadIdx.x;
  const int* xr = x + (size_t)row*ROWI;

#define PSL(SL, D) pout[(size_t)((SL)*33 + (D))*16384 + row]
  float mG[32], mD[32], mA[32];
  #pragma unroll
  for (int d = 0; d < 32; ++d) {
    mG[d] = PSL(0, d);
    mD[d] = PSL(1, d);
    mA[d] = PSL(2, d) + PSL(3, d) + PSL(4, d);
  }
  float cG = PSL(0, 32);
  float cD = PSL(1, 32);
  float cA = PSL(2, 32) + PSL(3, 32) + PSL(4, 32);
#undef PSL

  // tail actor columns 10240, 10241 (= Wa cols 8028, 8029)
  {
    const float t0 = (float)xr[10240], t1 = (float)xr[10241];
    cA += t0 + t1;
    #pragma unroll
    for (int d = 0; d < 32; ++d)
      mA[d] = fmaf(t1, Wa[d*8030 + 8029], fmaf(t0, Wa[d*8030 + 8028], mA[d]));
  }

  #pragma unroll
  for (int d = 0; d < 32; ++d) { mG[d] /= cG; mD[d] /= cD; mA[d] /= cA; }

  const int ridx = xr[0];
  const int gi = xr[10242], ai = xr[10243], oi = xr[10244], ari = xr[10245];
  const float* Pr = P + (size_t)ridx*64;
  const float* Pg = P + (size_t)(6 + gi)*64;
  const float* Pa = P + (size_t)(8 + ai)*64;
  const float* Po = P + (size_t)(15 + oi)*64;
  const float* Pz = P + (size_t)(36 + ari)*64;

  float h1[64];
  #pragma unroll
  for (int o = 0; o < 64; ++o)
    h1[o] = b1[o] + ((Pr[o] + Pg[o]) + (Pa[o] + Po[o])) + Pz[o];

  #pragma unroll
  for (int o = 0; o < 64; ++o) {
    const float* w = W1 + o*256;
    float a = h1[o];
    #pragma unroll
    for (int d = 0; d < 32; ++d) a = fmaf(mG[d], w[32+d], a);
    #pragma unroll
    for (int d = 0; d < 32; ++d) a = fmaf(mD[d], w[64+d], a);
    #pragma unroll
    for (int d = 0; d < 32; ++d) a = fmaf(mA[d], w[96+d], a);
    h1[o] = fmaxf(a, 0.f);
  }

  float h2[64];
  #pragma unroll
  for (int o2 = 0; o2 < 64; ++o2) h2[o2] = b2[o2];
  #pragma unroll
  for (int o = 0; o < 64; ++o) {
    const float h = h1[o];
    const float* wr = W2t + o*64;
    #pragma unroll
    for (int o2 = 0; o2 < 64; ++o2) h2[o2] = fmaf(h, wr[o2], h2[o2]);
  }
  float acc = bout[0];
  #pragma unroll
  for (int o2 = 0; o2 < 64; ++o2) acc = fmaf(fmaxf(h2[o2], 0.f), Wout[o2], acc);
  out[row] = acc;
}

// ---------------- launcher ----------------
extern "C" void kernel_launch(void* const* d_in, const int* in_sizes, int n_in,
                              void* d_out, int out_size, void* d_ws, size_t ws_size,
                              hipStream_t stream) {
  (void)in_sizes; (void)n_in; (void)out_size; (void)ws_size;
  const int*   x        = (const int*)  d_in[0];
  const float* emb_rate = (const float*)d_in[1];
  const float* W_genre  = (const float*)d_in[2];
  const float* W_dir    = (const float*)d_in[3];
  const float* W_actor  = (const float*)d_in[4];
  const float* emb_gen  = (const float*)d_in[5];
  const float* emb_age  = (const float*)d_in[6];
  const float* emb_occ  = (const float*)d_in[7];
  const float* emb_area = (const float*)d_in[8];
  const float* W1   = (const float*)d_in[9];
  const float* b1   = (const float*)d_in[10];
  const float* W2   = (const float*)d_in[11];
  const float* b2   = (const float*)d_in[12];
  const float* Wout = (const float*)d_in[13];
  const float* bout = (const float*)d_in[14];
  float* outp = (float*)d_out;

  float* ws   = (float*)d_ws;
  float* pout = ws;                                   // NSLICE*33*16384 floats
  u16*   Bf   = (u16*)(ws + POUT_F);                  // 992 KB, 16B-aligned
  float* P    = (float*)(Bf + BF_U16);
  float* W2t  = P + PTAB_F;

  prep_bf<<<(NSLOT*3*64 + 255)/256, 256, 0, stream>>>(W_genre, W_dir, W_actor, Bf);
  prep_p<<<(PTAB_F + 255)/256, 256, 0, stream>>>(emb_rate, emb_gen, emb_age, emb_occ,
                                                 emb_area, W1, P);
  prep_w2t<<<16, 256, 0, stream>>>(W2, W2t);

  dim3 gm(NROW/64, 3);
  kmain<<<gm, 256, 0, stream>>>(x, Bf, pout);
  k2<<<NROW/64, 64, 0, stream>>>(x, pout, W_actor, P, W1, b1, W2t, b2, Wout, bout, outp);
}

// Round 8
// 289.244 us; speedup vs baseline: 1.7758x; 1.7758x over previous
//
#include <hip/hip_runtime.h>

#define NROW 16384
#define ROWI 10246
#define NSLICE 6                  // [half][seg]: half*3 + {G,D,A}
#define POUT_F (NSLICE*33*16384)
#define NSLOT 323                 // B slots: 0..320 tiles, 321=D@t0, 322=A@t69
#define BF_U16 ((size_t)NSLOT*128*8)
#define BITS_W 160
#define BITS_U32 ((size_t)NROW*BITS_W)
#define PTAB_ROWS 3438
#define PTAB_F (PTAB_ROWS*64)

typedef unsigned int u32;
typedef unsigned long long u64;
typedef unsigned short u16;
typedef short short8 __attribute__((ext_vector_type(8)));
typedef float f32x4 __attribute__((ext_vector_type(4)));

union AFrag { u32 u[4]; short8 s; };
union BFrag { uint4 v; short8 s; };

// ---------------- prep: B fragment table (bf16, MFMA layout) ----------------
// Frag id = (slot*2 + f)*64 + lane ; elem e: k = t*32 + (lane>>4)*8 + e,
// d = f*16 + (lane&15). Masked to the slot's segment (zeros elsewhere).
__global__ void prep_bf(const float* __restrict__ Wg, const float* __restrict__ Wd,
                        const float* __restrict__ Wa, u16* __restrict__ Bf) {
  int id = blockIdx.x*256 + threadIdx.x;
  if (id >= NSLOT*128) return;
  int lane = id & 63, f = (id >> 6) & 1, slot = id >> 7;
  int t   = (slot == 321) ? 0 : (slot == 322) ? 69 : slot;
  int seg = (slot == 0) ? 0 : (slot <= 69) ? 1 : (slot <= 320) ? 2
            : (slot == 321) ? 1 : 2;                  // 0=G,1=D,2=A
  int clo = (seg == 0) ? 1  : (seg == 1) ? 26   : 2212;
  int chi = (seg == 0) ? 26 : (seg == 1) ? 2212 : 10242;
  int d  = f*16 + (lane & 15);
  int kb = t*32 + (lane >> 4)*8;
  u16 o[8];
  #pragma unroll
  for (int e = 0; e < 8; ++e) {
    int c = kb + e;
    float v = 0.f;
    if (c >= clo && c < chi) {
      if (seg == 0)      v = Wg[d*25   + (c-1)];
      else if (seg == 1) v = Wd[d*2186 + (c-26)];
      else               v = Wa[d*8030 + (c-2212)];
    }
    u32 bits = __float_as_uint(v);                    // RNE float->bf16
    o[e] = (u16)((bits + 0x7FFFu + ((bits >> 16) & 1u)) >> 16);
  }
  uint4 w;
  w.x = (u32)o[0] | ((u32)o[1] << 16);
  w.y = (u32)o[2] | ((u32)o[3] << 16);
  w.z = (u32)o[4] | ((u32)o[5] << 16);
  w.w = (u32)o[6] | ((u32)o[7] << 16);
  *(uint4*)&Bf[(size_t)id*8] = w;
}

// ---------------- prep: folded index-embedding table ----------------
__global__ void prep_p(const float* __restrict__ er, const float* __restrict__ eg,
                       const float* __restrict__ ea, const float* __restrict__ eo,
                       const float* __restrict__ ez, const float* __restrict__ W1,
                       float* __restrict__ P) {
  int id = blockIdx.x*256 + threadIdx.x;
  if (id >= PTAB_F) return;
  int r = id >> 6, o = id & 63;
  const float* emb; int woff;
  if (r < 6)       { emb = er + r*32;       woff = 0;   }
  else if (r < 8)  { emb = eg + (r-6)*32;   woff = 128; }
  else if (r < 15) { emb = ea + (r-8)*32;   woff = 160; }
  else if (r < 36) { emb = eo + (r-15)*32;  woff = 192; }
  else             { emb = ez + (r-36)*32;  woff = 224; }
  const float* w = W1 + o*256 + woff;
  float s = 0.f;
  #pragma unroll
  for (int c2 = 0; c2 < 32; ++c2) s += emb[c2]*w[c2];
  P[id] = s;
}

__global__ void prep_w2t(const float* __restrict__ W2, float* __restrict__ W2t) {
  int id = blockIdx.x*256 + threadIdx.x;
  if (id >= 64*64) return;
  int o = id >> 6, o2 = id & 63;
  W2t[o*64 + o2] = W2[o2*64 + o];
}

// ---------------- pack: linear-stream x -> bit matrix ----------------
// Wave = one row; per iteration 64 lanes read 64 consecutive ints (256 B
// contiguous, back-to-back along the row) -> __ballot -> 2 u32 words.
// bits[row][t] bit j = x[row][t*32 + j]  (cols [0,10240) only).
__global__ __launch_bounds__(256) void pack(const int* __restrict__ x,
                                            u32* __restrict__ bits) {
  const int lane = threadIdx.x & 63;
  const int row  = blockIdx.x*4 + (threadIdx.x >> 6);
  const int* base = x + (size_t)row*ROWI;
  u32* obase = bits + (size_t)row*BITS_W;
  #pragma unroll
  for (int p = 0; p < 3; ++p) {
    const int nit = (p == 2) ? 16 : 32;      // words [64p, 64p+2*nit)
    u32 keep = 0;
    #pragma unroll 4
    for (int i = 0; i < nit; ++i) {
      const int v = base[p*4096 + i*64 + lane];
      const u64 b = __ballot(v != 0);
      keep = (lane == 2*i)     ? (u32)b         : keep;
      keep = (lane == 2*i + 1) ? (u32)(b >> 32) : keep;
    }
    if (p < 2 || lane < 32) obase[p*64 + lane] = keep;   // coalesced u32 store
  }
}

// ---------------- fused MFMA bag kernel (A from bit matrix) ----------------
// Wave = 16 rows; block = 4 waves = 64 rows; blockIdx.y = K-half.
// A: row = lane&15, k = (lane>>4)*8+e (from bits).  D: d = lane&15, row=(lane>>4)*4+reg.
__global__ __launch_bounds__(256, 2) void kmain(
    const u32* __restrict__ bits, const u16* __restrict__ Bf, float* __restrict__ pout) {
  const int lane = threadIdx.x & 63;
  const int wv   = threadIdx.x >> 6;
  const int half = blockIdx.y;
  const int row0w = blockIdx.x*64 + wv*16;
  const int r = lane & 15, g = lane >> 4;
  const int g8 = g*8;

  const int tb = half*160, te = tb + 160;

  const u32*   pW = bits + (size_t)(row0w + r)*BITS_W;   // per-lane bit row
  const uint4* pB = (const uint4*)Bf;                    // frag id

  f32x4 z = {0.f,0.f,0.f,0.f};
  f32x4 aG0=z, aG1=z, aD0=z, aD1=z, aA0=z, aA1=z;
  int cG = 0, cD = 0, cA = 0;

  u32 wC, wN1, wN2 = 0;
  uint4 bC0, bC1, bN0, bN1;
  wC  = pW[tb];
  wN1 = pW[tb+1];
  bC0 = pB[(tb*2)*64 + lane];
  bC1 = pB[(tb*2+1)*64 + lane];

  for (int t = tb; t < te; ++t) {
    if (t + 2 < te) wN2 = pW[t+2];
    if (t + 1 < te) {
      bN0 = pB[((t+1)*2)*64 + lane];
      bN1 = pB[((t+1)*2+1)*64 + lane];
    }

    const u32 byte = (wC >> g8) & 0xFFu;
    AFrag af;
    af.u[0] = __umul24(((byte     ) & 1u) + (((byte >> 1) & 1u) << 16), 0x3F80u);
    af.u[1] = __umul24(((byte >> 2) & 1u) + (((byte >> 3) & 1u) << 16), 0x3F80u);
    af.u[2] = __umul24(((byte >> 4) & 1u) + (((byte >> 5) & 1u) << 16), 0x3F80u);
    af.u[3] = __umul24(((byte >> 6) & 1u) + (((byte >> 7) & 1u) << 16), 0x3F80u);
    const int csum = __popc(byte);
    BFrag b0, b1; b0.v = bC0; b1.v = bC1;

    if (t == 0) {
      aG0 = __builtin_amdgcn_mfma_f32_16x16x32_bf16(af.s, b0.s, aG0, 0, 0, 0);
      aG1 = __builtin_amdgcn_mfma_f32_16x16x32_bf16(af.s, b1.s, aG1, 0, 0, 0);
      BFrag e0, e1;
      e0.v = pB[(321*2)*64 + lane];
      e1.v = pB[(321*2+1)*64 + lane];
      aD0 = __builtin_amdgcn_mfma_f32_16x16x32_bf16(af.s, e0.s, aD0, 0, 0, 0);
      aD1 = __builtin_amdgcn_mfma_f32_16x16x32_bf16(af.s, e1.s, aD1, 0, 0, 0);
      #pragma unroll
      for (int j = 0; j < 4; ++j) {                 // cols g8+2j(+1): G=[1,26) D=[26,32)
        const int c0 = g8 + 2*j, c1 = c0 + 1;
        const int v0 = (byte >> (2*j)) & 1, v1 = (byte >> (2*j+1)) & 1;
        cG += (c0 >= 1 && c0 < 26) ? v0 : 0;
        cG += (c1 < 26) ? v1 : 0;
        cD += (c0 >= 26) ? v0 : 0;
        cD += (c1 >= 26) ? v1 : 0;
      }
    } else if (t == 69) {                           // cols 2208..2211 D, 2212..2239 A
      aD0 = __builtin_amdgcn_mfma_f32_16x16x32_bf16(af.s, b0.s, aD0, 0, 0, 0);
      aD1 = __builtin_amdgcn_mfma_f32_16x16x32_bf16(af.s, b1.s, aD1, 0, 0, 0);
      BFrag e0, e1;
      e0.v = pB[(322*2)*64 + lane];
      e1.v = pB[(322*2+1)*64 + lane];
      aA0 = __builtin_amdgcn_mfma_f32_16x16x32_bf16(af.s, e0.s, aA0, 0, 0, 0);
      aA1 = __builtin_amdgcn_mfma_f32_16x16x32_bf16(af.s, e1.s, aA1, 0, 0, 0);
      #pragma unroll
      for (int j = 0; j < 4; ++j) {                 // D iff g==0 && j<2
        const int s01 = ((byte >> (2*j)) & 1) + ((byte >> (2*j+1)) & 1);
        if (j < 2) { cD += (g == 0) ? s01 : 0; cA += (g == 0) ? 0 : s01; }
        else       { cA += s01; }
      }
    } else if (t < 69) {
      aD0 = __builtin_amdgcn_mfma_f32_16x16x32_bf16(af.s, b0.s, aD0, 0, 0, 0);
      aD1 = __builtin_amdgcn_mfma_f32_16x16x32_bf16(af.s, b1.s, aD1, 0, 0, 0);
      cD += csum;
    } else {
      aA0 = __builtin_amdgcn_mfma_f32_16x16x32_bf16(af.s, b0.s, aA0, 0, 0, 0);
      aA1 = __builtin_amdgcn_mfma_f32_16x16x32_bf16(af.s, b1.s, aA1, 0, 0, 0);
      cA += csum;
    }

    wC = wN1; wN1 = wN2;
    bC0 = bN0; bC1 = bN1;
  }

  // full per-row counts: reduce over the 4 k-groups (lanes l, l^16, l^32, l^48)
  cG += __shfl_xor(cG, 16); cG += __shfl_xor(cG, 32);
  cD += __shfl_xor(cD, 16); cD += __shfl_xor(cD, 32);
  cA += __shfl_xor(cA, 16); cA += __shfl_xor(cA, 32);

  const int sl0 = half*3;
#define STO(A0, A1, SL) do {                                                   \
    float* bp = pout + (size_t)(SL)*33*16384;                                  \
    _Pragma("unroll")                                                          \
    for (int q2 = 0; q2 < 4; ++q2) {                                           \
      bp[(size_t)r*16384      + row0w + g*4 + q2] = A0[q2];                    \
      bp[(size_t)(16+r)*16384 + row0w + g*4 + q2] = A1[q2];                    \
    } } while (0)
  STO(aG0, aG1, sl0+0);
  STO(aD0, aD1, sl0+1);
  STO(aA0, aA1, sl0+2);
#undef STO
  if (lane < 16) {
    pout[((size_t)(sl0+0)*33 + 32)*16384 + row0w + lane] = (float)cG;
    pout[((size_t)(sl0+1)*33 + 32)*16384 + row0w + lane] = (float)cD;
    pout[((size_t)(sl0+2)*33 + 32)*16384 + row0w + lane] = (float)cA;
  }
}

// ---------------- reduce + tail + MLP kernel ----------------
__global__ __launch_bounds__(64, 1) void k2(
    const int* __restrict__ x, const float* __restrict__ pout,
    const float* __restrict__ Wa, const float* __restrict__ P,
    const float* __restrict__ W1, const float* __restrict__ b1,
    const float* __restrict__ W2t, const float* __restrict__ b2,
    const float* __restrict__ Wout, const float* __restrict__ bout,
    float* __restrict__ out) {
  const int row = blockIdx.x*64 + threadIdx.x;
  const int* xr = x + (size_t)row*ROWI;

#define PSL(SL, D) pout[(size_t)((SL)*33 + (D))*16384 + row]
  float mG[32], mD[32], mA[32];
  #pragma unroll
  for (int d = 0; d < 32; ++d) {
    mG[d] = PSL(0, d) + PSL(3, d);
    mD[d] = PSL(1, d) + PSL(4, d);
    mA[d] = PSL(2, d) + PSL(5, d);
  }
  float cG = PSL(0, 32) + PSL(3, 32);
  float cD = PSL(1, 32) + PSL(4, 32);
  float cA = PSL(2, 32) + PSL(5, 32);
#undef PSL

  // tail actor columns 10240, 10241 (= Wa cols 8028, 8029)
  {
    const float t0 = (float)xr[10240], t1 = (float)xr[10241];
    cA += t0 + t1;
    #pragma unroll
    for (int d = 0; d < 32; ++d)
      mA[d] = fmaf(t1, Wa[d*8030 + 8029], fmaf(t0, Wa[d*8030 + 8028], mA[d]));
  }

  #pragma unroll
  for (int d = 0; d < 32; ++d) { mG[d] /= cG; mD[d] /= cD; mA[d] /= cA; }

  const int ridx = xr[0];
  const int gi = xr[10242], ai = xr[10243], oi = xr[10244], ari = xr[10245];
  const float* Pr = P + (size_t)ridx*64;
  const float* Pg = P + (size_t)(6 + gi)*64;
  const float* Pa = P + (size_t)(8 + ai)*64;
  const float* Po = P + (size_t)(15 + oi)*64;
  const float* Pz = P + (size_t)(36 + ari)*64;

  float h1[64];
  #pragma unroll
  for (int o = 0; o < 64; ++o)
    h1[o] = b1[o] + ((Pr[o] + Pg[o]) + (Pa[o] + Po[o])) + Pz[o];

  #pragma unroll
  for (int o = 0; o < 64; ++o) {
    const float* w = W1 + o*256;
    float a = h1[o];
    #pragma unroll
    for (int d = 0; d < 32; ++d) a = fmaf(mG[d], w[32+d], a);
    #pragma unroll
    for (int d = 0; d < 32; ++d) a = fmaf(mD[d], w[64+d], a);
    #pragma unroll
    for (int d = 0; d < 32; ++d) a = fmaf(mA[d], w[96+d], a);
    h1[o] = fmaxf(a, 0.f);
  }

  float h2[64];
  #pragma unroll
  for (int o2 = 0; o2 < 64; ++o2) h2[o2] = b2[o2];
  #pragma unroll
  for (int o = 0; o < 64; ++o) {
    const float h = h1[o];
    const float* wr = W2t + o*64;
    #pragma unroll
    for (int o2 = 0; o2 < 64; ++o2) h2[o2] = fmaf(h, wr[o2], h2[o2]);
  }
  float acc = bout[0];
  #pragma unroll
  for (int o2 = 0; o2 < 64; ++o2) acc = fmaf(fmaxf(h2[o2], 0.f), Wout[o2], acc);
  out[row] = acc;
}

// ---------------- launcher ----------------
extern "C" void kernel_launch(void* const* d_in, const int* in_sizes, int n_in,
                              void* d_out, int out_size, void* d_ws, size_t ws_size,
                              hipStream_t stream) {
  (void)in_sizes; (void)n_in; (void)out_size; (void)ws_size;
  const int*   x        = (const int*)  d_in[0];
  const float* emb_rate = (const float*)d_in[1];
  const float* W_genre  = (const float*)d_in[2];
  const float* W_dir    = (const float*)d_in[3];
  const float* W_actor  = (const float*)d_in[4];
  const float* emb_gen  = (const float*)d_in[5];
  const float* emb_age  = (const float*)d_in[6];
  const float* emb_occ  = (const float*)d_in[7];
  const float* emb_area = (const float*)d_in[8];
  const float* W1   = (const float*)d_in[9];
  const float* b1   = (const float*)d_in[10];
  const float* W2   = (const float*)d_in[11];
  const float* b2   = (const float*)d_in[12];
  const float* Wout = (const float*)d_in[13];
  const float* bout = (const float*)d_in[14];
  float* outp = (float*)d_out;

  float* ws   = (float*)d_ws;
  float* pout = ws;                                   // 6*33*16384 floats
  u32*   bits = (u32*)(ws + POUT_F);                  // 16384*160 u32 = 10.5 MB
  u16*   Bf   = (u16*)(bits + BITS_U32);              // 646 KB, 16B-aligned
  float* P    = (float*)(Bf + BF_U16);
  float* W2t  = P + PTAB_F;

  prep_bf<<<(NSLOT*128 + 255)/256, 256, 0, stream>>>(W_genre, W_dir, W_actor, Bf);
  prep_p<<<(PTAB_F + 255)/256, 256, 0, stream>>>(emb_rate, emb_gen, emb_age, emb_occ,
                                                 emb_area, W1, P);
  prep_w2t<<<16, 256, 0, stream>>>(W2, W2t);

  pack<<<NROW/4, 256, 0, stream>>>(x, bits);

  dim3 gm(NROW/64, 2);
  kmain<<<gm, 256, 0, stream>>>(bits, Bf, pout);
  k2<<<NROW/64, 64, 0, stream>>>(x, pout, W_actor, P, W1, b1, W2t, b2, Wout, bout, outp);
}